// Round 9
// baseline (197.091 us; speedup 1.0000x reference)
//
#include <hip/hip_runtime.h>
#include <hip/hip_bf16.h>

// InfoNCE loss, N=4096, D=1024, TEMP=0.07.
// loss = mean_i( -pos_i + lse_i ), lse over sim rows with diagonal masked.
// Fixed-max LSE (rows unit-norm -> sim <= 1/T): partials are order-independent.
// Symmetry via 128x128 tiles, upper triangle (J >= I).
//
// R9: split operand paths. A staged in LDS (ring-of-3 BK=32 slots, 24 KiB,
// zero-conflict XOR swizzle); B-fragments loaded global->register directly
// (per-lane 16B contiguous, one-step register prefetch) -- halves LDS traffic,
// moves B onto the idle VMEM pipe. Counted mixed-FIFO vmcnt gates (10 steady,
// 2/6 peeled). Plane-store epilogue (no atomics), reduce+finalize fused.

typedef __attribute__((ext_vector_type(8))) short bf16x8;
typedef __attribute__((ext_vector_type(4))) float f32x4;

#define NN 4096
#define TWO_N 8192
#define DIM 1024
#define TEMP_INV 14.285714285714286f
#define EXP_SCALE 20.609929155566303f /* log2(e)/0.07 */
#define NT 64     /* tiles of 128 per dim */
#define NBLK 2080 /* 64*65/2 upper-tri tiles; 2080 % 8 == 0 -> bijective */
#define SLOT 4096 /* shorts per A slot: 128 rows x 32 k (8 KB) */
#define NPLANE 256

#define GLD16(g, l)                                                          \
  __builtin_amdgcn_global_load_lds(                                          \
      (const __attribute__((address_space(1))) void*)(g),                    \
      (__attribute__((address_space(3))) void*)(l), 16, 0, 0)

__device__ __forceinline__ unsigned short f2bf(float f) {
  unsigned int u = __float_as_uint(f);
  u += 0x7fffu + ((u >> 16) & 1u);  // RNE
  return (unsigned short)(u >> 16);
}

// Fused: fp32->bf16 cast of z=[z1;z2] AND pos[row]=dot(z1,z2)/T (one 32MB read).
__global__ __launch_bounds__(256) void prep_kernel(
    const float* __restrict__ z1, const float* __restrict__ z2,
    unsigned short* __restrict__ zb, float* __restrict__ pos) {
  const int row = blockIdx.x, t = threadIdx.x;
  float4 a = ((const float4*)(z1 + (size_t)row * DIM))[t];
  float4 b = ((const float4*)(z2 + (size_t)row * DIM))[t];
  ushort4 ua = {f2bf(a.x), f2bf(a.y), f2bf(a.z), f2bf(a.w)};
  ushort4 ub = {f2bf(b.x), f2bf(b.y), f2bf(b.z), f2bf(b.w)};
  ((ushort4*)(zb + (size_t)row * DIM))[t] = ua;
  ((ushort4*)(zb + (size_t)(NN + row) * DIM))[t] = ub;
  float s = a.x * b.x + a.y * b.y + a.z * b.z + a.w * b.w;
#pragma unroll
  for (int off = 1; off < 64; off <<= 1) s += __shfl_xor(s, off);
  __shared__ float tmp[4];
  if ((t & 63) == 0) tmp[t >> 6] = s;
  __syncthreads();
  if (t == 0) pos[row] = (tmp[0] + tmp[1] + tmp[2] + tmp[3]) * TEMP_INV;
}

__global__ __launch_bounds__(256, 3) void lse_kernel(
    const unsigned short* __restrict__ zb, float* __restrict__ part) {
  __shared__ unsigned short lds[3 * SLOT];  // 24 KiB (A only)
  // ---- tile decode: XCD swizzle -> upper-tri (I, J), J >= I ----
  int u = ((int)blockIdx.x & 7) * (NBLK / 8) + ((int)blockIdx.x >> 3);
  int I = 0, rem = u;
  while (rem >= NT - I) { rem -= NT - I; ++I; }
  const int J = I + rem;
  const int rowA0 = I * 128, colB0 = J * 128;
  const bool diag = (I == J);

  const int t = threadIdx.x;
  const int wave = t >> 6, lane = t & 63;
  const int wm = wave >> 1, wn = wave & 1;  // 2x2 waves, each 64x64 out
  const int lo = lane & 15, hi = lane >> 4;

  // ---- A staging: 2 chunks (16B) per thread per slot, inverse-XOR source ----
  int oA[2];
#pragma unroll
  for (int i = 0; i < 2; ++i) {
    int c = i * 256 + wave * 64 + lane, row = c >> 2, p = c & 3;
    oA[i] = (rowA0 + row) * DIM + (p ^ ((row >> 1) & 3)) * 8;
  }

  // ---- A read-side swizzle; B direct-global per-lane base pointers ----
  const int sx = (hi ^ ((lo >> 1) & 3)) * 8;  // swizzled 16B group
  const int arow0 = wm * 64 + lo;             // + m*16
  const unsigned short* gBn[4];
#pragma unroll
  for (int n = 0; n < 4; ++n)
    gBn[n] = zb + (size_t)(colB0 + wn * 64 + n * 16 + lo) * DIM + hi * 8;

  f32x4 acc[4][4];
#pragma unroll
  for (int m = 0; m < 4; ++m)
#pragma unroll
    for (int n = 0; n < 4; ++n) acc[m][n] = (f32x4){0.f, 0.f, 0.f, 0.f};

#define STAGE(dst_, k_)                                                       \
  {                                                                           \
    const unsigned short* gk = zb + (size_t)((k_) & 31) * 32;                 \
    GLD16(gk + oA[0], (dst_) + wave * 512);                                   \
    GLD16(gk + oA[1], (dst_) + 2048 + wave * 512);                            \
  }

  // One K-step. gate_ = counted vmcnt (string); BC = current B frags,
  // BN = next-step B frags (register double-buffer).
#define STEP(s_, gate_, BC, BN)                                               \
  asm volatile("s_waitcnt vmcnt(" gate_ ")" ::: "memory");                    \
  __builtin_amdgcn_s_barrier(); /* publish slot s; free slot s-1 (=sl2) */    \
  __builtin_amdgcn_sched_barrier(0);                                          \
  STAGE(sl2, (s_) + 2);                                                       \
  _Pragma("unroll") for (int n = 0; n < 4; ++n)                               \
      BN[n] = *(const bf16x8*)(gBn[n] + ((s_) + 1) * 32);                     \
  __builtin_amdgcn_s_setprio(1);                                              \
  _Pragma("unroll") for (int m = 0; m < 4; ++m) {                             \
    bf16x8 af = *(const bf16x8*)(sl0 + (arow0 + m * 16) * 32 + sx);           \
    _Pragma("unroll") for (int n = 0; n < 4; ++n)                             \
        acc[m][n] = __builtin_amdgcn_mfma_f32_16x16x32_bf16(af, BC[n],        \
                                                            acc[m][n], 0, 0, 0); \
  }                                                                           \
  __builtin_amdgcn_s_setprio(0);                                              \
  { unsigned short* r_ = sl0; sl0 = sl1; sl1 = sl2; sl2 = r_; }

  unsigned short* sl0 = lds;
  unsigned short* sl1 = lds + SLOT;
  unsigned short* sl2 = lds + 2 * SLOT;

  bf16x8 bgX[4], bgY[4];
  // prologue: B(0) first (oldest in FIFO), then A slots 0,1.
#pragma unroll
  for (int n = 0; n < 4; ++n) bgX[n] = *(const bf16x8*)(gBn[n]);
  STAGE(sl0, 0);
  STAGE(sl1, 1);

  // Peeled gates: s=0 -> vmcnt(2) (st1 newer than st0); s=1 -> vmcnt(6)
  // (st2+B1 newer than st1); steady (s>=2) -> vmcnt(10) (B(s-1)+st(s+1)+B(s)
  // newer than st(s)).
  STEP(0, "2", bgX, bgY);
  STEP(1, "6", bgY, bgX);
#pragma unroll 1
  for (int s = 2; s < 32; s += 2) {
    STEP(s, "10", bgX, bgY);
    STEP(s + 1, "10", bgY, bgX);
  }
  asm volatile("s_waitcnt vmcnt(0) lgkmcnt(0)" ::: "memory");  // drain dummies

  // ---- epilogue: e=exp((dot-1)/T), diag masked; row/col partial sums ----
  // NO atomics: plane stores (row partials keyed (J,wn); cols keyed (I,wm)).
  float* rplane = part + (size_t)(2 * J + wn) * TWO_N;
  float* cplane = part + (size_t)(128 + 2 * I + wm) * TWO_N;
  float csum[4] = {0.f, 0.f, 0.f, 0.f};
#pragma unroll
  for (int m = 0; m < 4; ++m) {
#pragma unroll
    for (int r = 0; r < 4; ++r) {
      const int grow = rowA0 + wm * 64 + m * 16 + hi * 4 + r;  // row=(lane>>4)*4+reg
      float s = 0.f;
#pragma unroll
      for (int n = 0; n < 4; ++n) {
        const int gcol = colB0 + wn * 64 + n * 16 + lo;        // col=lane&15
        float e = exp2f((acc[m][n][r] - 1.0f) * EXP_SCALE);
        if (grow == gcol) e = 0.f;  // mask self-similarity (diag tiles)
        s += e;
        csum[n] += e;
      }
      s += __shfl_xor(s, 1); s += __shfl_xor(s, 2);
      s += __shfl_xor(s, 4); s += __shfl_xor(s, 8);
      if (lo == 0) rplane[grow] = s;  // 4 lanes, 64 distinct rows per wave
    }
  }
  if (!diag) {  // off-diagonal tiles feed transposed rows via col sums
#pragma unroll
    for (int n = 0; n < 4; ++n) {
      float s = csum[n];
      s += __shfl_xor(s, 16); s += __shfl_xor(s, 32);
      if (hi == 0) cplane[colB0 + wn * 64 + n * 16 + lo] = s;  // 16 lanes
    }
  }
#undef STEP
#undef STAGE
}

// Fold 256 partial planes -> per-row term -> mean, in one kernel.
// 32 blocks x 256 threads, one row each; out zeroed before launch.
__global__ __launch_bounds__(256) void reduce_finalize_kernel(
    const float* __restrict__ part, const float* __restrict__ pos,
    float* __restrict__ out) {
  const int i = blockIdx.x * 256 + threadIdx.x;
  float s = 0.f;
#pragma unroll 8
  for (int p = 0; p < NPLANE; ++p) s += part[(size_t)p * TWO_N + i];
  float term = TEMP_INV + logf(s) - pos[i & (NN - 1)];
#pragma unroll
  for (int off = 1; off < 64; off <<= 1) term += __shfl_xor(term, off);
  __shared__ float tmp[4];
  const int t = threadIdx.x;
  if ((t & 63) == 0) tmp[t >> 6] = term;
  __syncthreads();
  if (t == 0)
    atomicAdd(out, (tmp[0] + tmp[1] + tmp[2] + tmp[3]) * (1.0f / (float)TWO_N));
}

extern "C" void kernel_launch(void* const* d_in, const int* in_sizes, int n_in,
                              void* d_out, int out_size, void* d_ws, size_t ws_size,
                              hipStream_t stream) {
  const float* z1 = (const float*)d_in[0];
  const float* z2 = (const float*)d_in[1];
  float* out = (float*)d_out;

  char* ws = (char*)d_ws;
  unsigned short* zb = (unsigned short*)ws;            // 16 MB bf16 z
  size_t off = (size_t)TWO_N * DIM * 2;
  float* part = (float*)(ws + off);                    // 8 MB: 256 x 8192 f32
  off += (size_t)NPLANE * TWO_N * 4;
  float* pos = (float*)(ws + off);                     // 16 KB

  hipMemsetAsync(part, 0, (size_t)NPLANE * TWO_N * 4, stream);
  hipMemsetAsync(out, 0, sizeof(float), stream);
  prep_kernel<<<NN, 256, 0, stream>>>(z1, z2, zb, pos);
  lse_kernel<<<NBLK, 256, 0, stream>>>(zb, part);
  reduce_finalize_kernel<<<TWO_N / 256, 256, 0, stream>>>(part, pos, out);
}

// Round 10
// 129.679 us; speedup vs baseline: 1.5198x; 1.5198x over previous
//
#include <hip/hip_runtime.h>
#include <hip/hip_bf16.h>

// InfoNCE loss, N=4096, D=1024, TEMP=0.07.
// loss = mean_i( -pos_i + lse_i ), lse over sim rows with diagonal masked.
// Fixed-max LSE (rows unit-norm -> sim <= 1/T): partials order-independent.
// Symmetry via 256x256 tiles, upper triangle (J >= I), NBLK=528.
//
// R10: faithful m201-style 8-phase port. 8 waves (2Mx4N, 128x64 out each),
// BK=64 K-tiles double-buffered (2 x 64 KiB LDS), 4 phases per K-tile:
// {current-phase ds_reads (4 or 8 b128) + 1-2 half-tile stages -> bar ->
//  setprio+16 MFMA+setprio -> bar}; ONE counted vmcnt(4) gate per K-tile.
// (row&7) XOR swizzle on 128B rows, inverse-applied on global sources.
// Plane-store epilogue (no atomics), fused reduce+finalize.

typedef __attribute__((ext_vector_type(8))) short bf16x8;
typedef __attribute__((ext_vector_type(4))) float f32x4;

#define NN 4096
#define TWO_N 8192
#define DIM 1024
#define TEMP_INV 14.285714285714286f
#define EXP_SCALE 20.609929155566303f /* log2(e)/0.07 */
#define NTILE 32  /* 8192/256 */
#define NBLK 528  /* 32*33/2; 528 % 8 == 0 -> bijective XCD swizzle */
#define NPLANE 192

#define GLD16(g, l)                                                          \
  __builtin_amdgcn_global_load_lds(                                          \
      (const __attribute__((address_space(1))) void*)(g),                    \
      (__attribute__((address_space(3))) void*)(l), 16, 0, 0)

__device__ __forceinline__ unsigned short f2bf(float f) {
  unsigned int u = __float_as_uint(f);
  u += 0x7fffu + ((u >> 16) & 1u);  // RNE
  return (unsigned short)(u >> 16);
}

// Fused: fp32->bf16 cast of z=[z1;z2] AND pos[row]=dot(z1,z2)/T (one 32MB read).
__global__ __launch_bounds__(256) void prep_kernel(
    const float* __restrict__ z1, const float* __restrict__ z2,
    unsigned short* __restrict__ zb, float* __restrict__ pos) {
  const int row = blockIdx.x, t = threadIdx.x;
  float4 a = ((const float4*)(z1 + (size_t)row * DIM))[t];
  float4 b = ((const float4*)(z2 + (size_t)row * DIM))[t];
  ushort4 ua = {f2bf(a.x), f2bf(a.y), f2bf(a.z), f2bf(a.w)};
  ushort4 ub = {f2bf(b.x), f2bf(b.y), f2bf(b.z), f2bf(b.w)};
  ((ushort4*)(zb + (size_t)row * DIM))[t] = ua;
  ((ushort4*)(zb + (size_t)(NN + row) * DIM))[t] = ub;
  float s = a.x * b.x + a.y * b.y + a.z * b.z + a.w * b.w;
#pragma unroll
  for (int off = 1; off < 64; off <<= 1) s += __shfl_xor(s, off);
  __shared__ float tmp[4];
  if ((t & 63) == 0) tmp[t >> 6] = s;
  __syncthreads();
  if (t == 0) pos[row] = (tmp[0] + tmp[1] + tmp[2] + tmp[3]) * TEMP_INV;
}

__global__ __launch_bounds__(512, 2) void lse_kernel(
    const unsigned short* __restrict__ zb, float* __restrict__ part) {
  extern __shared__ unsigned char lds[];  // 2 bufs x (A 32KB + B 32KB) = 128 KiB
  // ---- tile decode: XCD swizzle -> upper-tri (I, J), J >= I ----
  int u = ((int)blockIdx.x & 7) * (NBLK / 8) + ((int)blockIdx.x >> 3);
  int I = 0, rem = u;
  while (rem >= NTILE - I) { rem -= NTILE - I; ++I; }
  const int J = I + rem;
  const int rowA0 = I * 256, colB0 = J * 256;
  const bool diag = (I == J);

  const int t = threadIdx.x;
  const int wave = t >> 6, lane = t & 63;
  const int wm = wave >> 2, wn = wave & 3;  // 2M x 4N waves, 128x64 out each
  const int lo = lane & 15, hi = lane >> 4;

  // ---- staging constants: half-tile = 128 rows x 64 k of one matrix (16KB),
  // 2 gld16/thread. Chunk c = l*512 + t: row r=c>>3, phys 16B-group p=c&7
  // holds logical group lg = p ^ (r&7) (inverse of read-side XOR). Since
  // 512 % 8 == 0, lg is the same for both loads; row offset l*64.
  const int r0 = t >> 3;
  const int lgrp = (t & 7) ^ (r0 & 7);
  const size_t soff = (size_t)r0 * DIM + lgrp * 8;  // shorts
  const unsigned short* gA = zb + (size_t)rowA0 * DIM + soff;
  const unsigned short* gB = zb + (size_t)colB0 * DIM + soff;
  const int dst0 = wave * 1024;  // byte offset inside a half-tile region

  // ---- read-side swizzled offsets (bytes). Row stride 128B; 16B-group
  // g = kk*4 + hi, phys = g ^ (row&7) = g ^ (lo&7). ----
  const int gp0 = ((0 + hi) ^ (lo & 7)) * 16;  // kk=0
  const int gp1 = ((4 + hi) ^ (lo & 7)) * 16;  // kk=1
  const int abase = (wm * 128 + lo) * 128;          // within A region (0..32KB)
  const int bbase = 32768 + (wn * 64 + lo) * 128;   // within B region

  f32x4 acc[8][4];
#pragma unroll
  for (int m = 0; m < 8; ++m)
#pragma unroll
    for (int n = 0; n < 4; ++n) acc[m][n] = (f32x4){0.f, 0.f, 0.f, 0.f};

#define BUFP(b_) (lds + (b_) * 65536)
#define STG_A(b_, h_, kt_)                                                    \
  {                                                                           \
    const unsigned short* s_ = gA + (size_t)((h_) * 128) * DIM + ((kt_) & 15) * 64; \
    unsigned char* d_ = BUFP(b_) + (h_) * 16384 + dst0;                       \
    GLD16(s_, d_);                                                            \
    GLD16(s_ + (size_t)64 * DIM, d_ + 8192);                                  \
  }
#define STG_B(b_, h_, kt_)                                                    \
  {                                                                           \
    const unsigned short* s_ = gB + (size_t)((h_) * 128) * DIM + ((kt_) & 15) * 64; \
    unsigned char* d_ = BUFP(b_) + 32768 + (h_) * 16384 + dst0;               \
    GLD16(s_, d_);                                                            \
    GLD16(s_ + (size_t)64 * DIM, d_ + 8192);                                  \
  }
#define RD_A(AF, b_, mlo_, gp_)                                               \
  {                                                                           \
    const unsigned char* p_ = BUFP(b_) + abase + (gp_);                       \
    _Pragma("unroll") for (int i = 0; i < 4; ++i)                             \
        AF[i] = *(const bf16x8*)(p_ + ((mlo_) + i) * 2048);                   \
  }
#define RD_B(BF, b_, gp_)                                                     \
  {                                                                           \
    const unsigned char* p_ = BUFP(b_) + bbase + (gp_);                       \
    _Pragma("unroll") for (int i = 0; i < 4; ++i)                             \
        BF[i] = *(const bf16x8*)(p_ + i * 2048);                              \
  }
#define MFMA16(mlo_, AF, BF)                                                  \
  __builtin_amdgcn_s_setprio(1);                                              \
  _Pragma("unroll") for (int i = 0; i < 4; ++i)                               \
    _Pragma("unroll") for (int n = 0; n < 4; ++n)                             \
        acc[(mlo_) + i][n] = __builtin_amdgcn_mfma_f32_16x16x32_bf16(         \
            AF[i], BF[n], acc[(mlo_) + i][n], 0, 0, 0);                       \
  __builtin_amdgcn_s_setprio(0);
#define FENCE __builtin_amdgcn_sched_barrier(0)
#define BAR __builtin_amdgcn_s_barrier()

  // GROUP(b_, t_): 4 phases processing K-tile t_ from buf b_.
  // Stage plan (liveness-audited): (t+1).a0 @ph1, (t+1).a1 @ph2 -> buf ~b
  // (free: tile t-1 consumed); (t+2).b0+b1 @ph4 -> buf b (b-slots last read
  // ph3-pre). Gate once per group: vmcnt(4) = the 2 ph4 half-tiles in flight.
#define GROUP(b_, t_)                                                         \
  {                                                                           \
    bf16x8 af[4], bf[4];                                                      \
    /* ph1: m0-3 x kk0 */                                                     \
    RD_A(af, b_, 0, gp0); RD_B(bf, b_, gp0);                                  \
    STG_A(1 - (b_), 0, (t_) + 1);                                             \
    FENCE; BAR; FENCE;                                                        \
    MFMA16(0, af, bf);                                                        \
    BAR; FENCE;                                                               \
    /* ph2: m4-7 x kk0 (B regs reused) */                                     \
    RD_A(af, b_, 4, gp0);                                                     \
    STG_A(1 - (b_), 1, (t_) + 1);                                             \
    FENCE; BAR; FENCE;                                                        \
    MFMA16(4, af, bf);                                                        \
    BAR; FENCE;                                                               \
    /* ph3: m0-3 x kk1 */                                                     \
    RD_A(af, b_, 0, gp1); RD_B(bf, b_, gp1);                                  \
    FENCE; BAR; FENCE;                                                        \
    MFMA16(0, af, bf);                                                        \
    BAR; FENCE;                                                               \
    /* ph4: m4-7 x kk1; stage next-next b halves; gate */                     \
    RD_A(af, b_, 4, gp1);                                                     \
    STG_B(b_, 0, (t_) + 2); STG_B(b_, 1, (t_) + 2);                           \
    FENCE; BAR; FENCE;                                                        \
    MFMA16(4, af, bf);                                                        \
    asm volatile("s_waitcnt vmcnt(4)" ::: "memory");                          \
    BAR; FENCE;                                                               \
  }

  // prologue: t0 full -> buf0; t1.b0,b1 -> buf1; gate t0 (4 newest in flight)
  STG_A(0, 0, 0); STG_A(0, 1, 0); STG_B(0, 0, 0); STG_B(0, 1, 0);
  STG_B(1, 0, 1); STG_B(1, 1, 1);
  asm volatile("s_waitcnt vmcnt(4)" ::: "memory");
  BAR; FENCE;

#pragma unroll 1
  for (int tt = 0; tt < 16; tt += 2) {
    GROUP(0, tt);
    GROUP(1, tt + 1);
  }
  asm volatile("s_waitcnt vmcnt(0) lgkmcnt(0)" ::: "memory");  // drain dummies

  // ---- epilogue: e=exp((dot-1)/T), diag masked; row/col partial sums ----
  // NO atomics: plane stores. Row partials keyed (J, wn) -> planes 0..127;
  // col partials keyed (I, wm) -> planes 128..191. Disjoint by construction.
  float* rplane = part + (size_t)(4 * J + wn) * TWO_N;
  float* cplane = part + (size_t)(128 + 2 * I + wm) * TWO_N;
  float csum[4] = {0.f, 0.f, 0.f, 0.f};
#pragma unroll
  for (int m = 0; m < 8; ++m) {
#pragma unroll
    for (int r = 0; r < 4; ++r) {
      const int grow = rowA0 + wm * 128 + m * 16 + hi * 4 + r;  // row=(lane>>4)*4+reg
      float s = 0.f;
#pragma unroll
      for (int n = 0; n < 4; ++n) {
        const int gcol = colB0 + wn * 64 + n * 16 + lo;         // col=lane&15
        float e = exp2f((acc[m][n][r] - 1.0f) * EXP_SCALE);
        if (grow == gcol) e = 0.f;  // mask self-similarity (diag tiles)
        s += e;
        csum[n] += e;
      }
      s += __shfl_xor(s, 1); s += __shfl_xor(s, 2);
      s += __shfl_xor(s, 4); s += __shfl_xor(s, 8);
      if (lo == 0) rplane[grow] = s;  // 4 lanes x 32 (m,r) = 128 rows/wave
    }
  }
  if (!diag) {  // off-diagonal tiles feed transposed rows via col sums
#pragma unroll
    for (int n = 0; n < 4; ++n) {
      float s = csum[n];
      s += __shfl_xor(s, 16); s += __shfl_xor(s, 32);
      if (hi == 0) cplane[colB0 + wn * 64 + n * 16 + lo] = s;  // 16 lanes x 4n
    }
  }
#undef GROUP
#undef MFMA16
#undef RD_A
#undef RD_B
#undef STG_A
#undef STG_B
#undef BUFP
#undef FENCE
#undef BAR
}

// Fold 192 partial planes -> per-row term -> mean, in one kernel.
// 32 blocks x 256 threads, one row each; out zeroed before launch.
__global__ __launch_bounds__(256) void reduce_finalize_kernel(
    const float* __restrict__ part, const float* __restrict__ pos,
    float* __restrict__ out) {
  const int i = blockIdx.x * 256 + threadIdx.x;
  float s = 0.f;
#pragma unroll 8
  for (int p = 0; p < NPLANE; ++p) s += part[(size_t)p * TWO_N + i];
  float term = TEMP_INV + logf(s) - pos[i & (NN - 1)];
#pragma unroll
  for (int off = 1; off < 64; off <<= 1) term += __shfl_xor(term, off);
  __shared__ float tmp[4];
  const int t = threadIdx.x;
  if ((t & 63) == 0) tmp[t >> 6] = term;
  __syncthreads();
  if (t == 0)
    atomicAdd(out, (tmp[0] + tmp[1] + tmp[2] + tmp[3]) * (1.0f / (float)TWO_N));
}

extern "C" void kernel_launch(void* const* d_in, const int* in_sizes, int n_in,
                              void* d_out, int out_size, void* d_ws, size_t ws_size,
                              hipStream_t stream) {
  const float* z1 = (const float*)d_in[0];
  const float* z2 = (const float*)d_in[1];
  float* out = (float*)d_out;

  char* ws = (char*)d_ws;
  unsigned short* zb = (unsigned short*)ws;            // 16 MB bf16 z
  size_t off = (size_t)TWO_N * DIM * 2;
  float* part = (float*)(ws + off);                    // 6 MB: 192 x 8192 f32
  off += (size_t)NPLANE * TWO_N * 4;
  float* pos = (float*)(ws + off);                     // 16 KB

  hipMemsetAsync(part, 0, (size_t)NPLANE * TWO_N * 4, stream);
  hipMemsetAsync(out, 0, sizeof(float), stream);
  prep_kernel<<<NN, 256, 0, stream>>>(z1, z2, zb, pos);
  lse_kernel<<<NBLK, 512, 131072, stream>>>(zb, part);
  reduce_finalize_kernel<<<TWO_N / 256, 256, 0, stream>>>(part, pos, out);
}

// Round 11
// 123.493 us; speedup vs baseline: 1.5960x; 1.0501x over previous
//
#include <hip/hip_runtime.h>
#include <hip/hip_bf16.h>

// InfoNCE loss, N=4096, D=1024, TEMP=0.07.
// loss = mean_i( -pos_i + lse_i ), lse over sim rows with diagonal masked.
// Fixed-max LSE (rows unit-norm -> sim <= 1/T): partials are order-independent.
// Symmetry via 128x128 tiles, upper triangle (J >= I).
//
// R11: occupancy push #2. R8 structure (128x128 tile, 4 waves 2x2, 64x64
// out/wave, zero-conflict XOR swizzle, plane-store epilogue) with ring-2
// double-buffer (32 KiB LDS) + __launch_bounds__(256,4) -> 4 blocks/CU =
// 16 waves/CU. Counted vmcnt(4) gate, 2 barriers/step. Reduce reads only
// the provably-written plane entries (Ji-bounded) -> part memset removed.

typedef __attribute__((ext_vector_type(8))) short bf16x8;
typedef __attribute__((ext_vector_type(4))) float f32x4;

#define NN 4096
#define TWO_N 8192
#define DIM 1024
#define TEMP_INV 14.285714285714286f
#define EXP_SCALE 20.609929155566303f /* log2(e)/0.07 */
#define NT 64     /* tiles of 128 per dim */
#define NBLK 2080 /* 64*65/2 upper-tri tiles; 2080 % 8 == 0 -> bijective */
#define SLOT 4096 /* shorts per slot: A 128x32 + B 128x32 (8 KB+8 KB = 16 KB) */

#define GLD16(g, l)                                                          \
  __builtin_amdgcn_global_load_lds(                                          \
      (const __attribute__((address_space(1))) void*)(g),                    \
      (__attribute__((address_space(3))) void*)(l), 16, 0, 0)

__device__ __forceinline__ unsigned short f2bf(float f) {
  unsigned int u = __float_as_uint(f);
  u += 0x7fffu + ((u >> 16) & 1u);  // RNE
  return (unsigned short)(u >> 16);
}

// Fused: fp32->bf16 cast of z=[z1;z2] AND pos[row]=dot(z1,z2)/T (one 32MB read).
__global__ __launch_bounds__(256) void prep_kernel(
    const float* __restrict__ z1, const float* __restrict__ z2,
    unsigned short* __restrict__ zb, float* __restrict__ pos) {
  const int row = blockIdx.x, t = threadIdx.x;
  float4 a = ((const float4*)(z1 + (size_t)row * DIM))[t];
  float4 b = ((const float4*)(z2 + (size_t)row * DIM))[t];
  ushort4 ua = {f2bf(a.x), f2bf(a.y), f2bf(a.z), f2bf(a.w)};
  ushort4 ub = {f2bf(b.x), f2bf(b.y), f2bf(b.z), f2bf(b.w)};
  ((ushort4*)(zb + (size_t)row * DIM))[t] = ua;
  ((ushort4*)(zb + (size_t)(NN + row) * DIM))[t] = ub;
  float s = a.x * b.x + a.y * b.y + a.z * b.z + a.w * b.w;
#pragma unroll
  for (int off = 1; off < 64; off <<= 1) s += __shfl_xor(s, off);
  __shared__ float tmp[4];
  if ((t & 63) == 0) tmp[t >> 6] = s;
  __syncthreads();
  if (t == 0) pos[row] = (tmp[0] + tmp[1] + tmp[2] + tmp[3]) * TEMP_INV;
}

__global__ __launch_bounds__(256, 4) void lse_kernel(
    const unsigned short* __restrict__ zb, float* __restrict__ part) {
  __shared__ unsigned short lds[2 * SLOT];  // 32 KiB -> 4+ blocks/CU (VGPR-capped)
  // ---- tile decode: XCD swizzle -> upper-tri (I, J), J >= I ----
  int u = ((int)blockIdx.x & 7) * (NBLK / 8) + ((int)blockIdx.x >> 3);
  int I = 0, rem = u;
  while (rem >= NT - I) { rem -= NT - I; ++I; }
  const int J = I + rem;
  const int rowA0 = I * 128, colB0 = J * 128;
  const bool diag = (I == J);

  const int t = threadIdx.x;
  const int wave = t >> 6, lane = t & 63;
  const int wm = wave >> 1, wn = wave & 1;  // 2x2 waves, each 64x64 out
  const int lo = lane & 15, hi = lane >> 4;

  // ---- staging: 2 A-chunks + 2 B-chunks (16B each) per thread per slot ----
  // slot layout (shorts): A[128 rows][32] at 0, B[128][32] at 4096. Chunk c
  // (16B): row=c>>2, phys group p=c&3 holds logical lg = p ^ ((row>>1)&3)
  // (inverse of the read-side XOR). LDS dest linear (wave-uniform + lane*16).
  int oA[2], oB[2];
#pragma unroll
  for (int i = 0; i < 2; ++i) {
    int c = i * 256 + wave * 64 + lane, row = c >> 2, p = c & 3;
    oA[i] = (rowA0 + row) * DIM + (p ^ ((row >> 1) & 3)) * 8;
    oB[i] = (colB0 + row) * DIM + (p ^ ((row >> 1) & 3)) * 8;
  }

  // ---- compute-side ds_read offsets (shorts), swizzle applied on read ----
  const int sx = (hi ^ ((lo >> 1) & 3)) * 8;  // swizzled 16B group
  const int arow0 = wm * 64 + lo;             // + m*16
  const int brow0 = wn * 64 + lo;             // + n*16

  f32x4 acc[4][4];
#pragma unroll
  for (int m = 0; m < 4; ++m)
#pragma unroll
    for (int n = 0; n < 4; ++n) acc[m][n] = (f32x4){0.f, 0.f, 0.f, 0.f};

#define STAGE(dst_, k_)                                                       \
  {                                                                           \
    const unsigned short* gk = zb + (size_t)((k_) & 31) * 32;                 \
    GLD16(gk + oA[0], (dst_) + wave * 512);                                   \
    GLD16(gk + oA[1], (dst_) + 2048 + wave * 512);                            \
    GLD16(gk + oB[0], (dst_) + 4096 + wave * 512);                            \
    GLD16(gk + oB[1], (dst_) + 4096 + 2048 + wave * 512);                     \
  }

  unsigned short* cur = lds;         // slot holding tile s
  unsigned short* oth = lds + SLOT;  // slot holding tile s-1 / stage target

  STAGE(cur, 0);
  asm volatile("s_waitcnt vmcnt(0)" ::: "memory");  // own slot-0 loads done

#pragma unroll 1
  for (int s = 0; s < DIM / 32; ++s) {
    __builtin_amdgcn_s_barrier();  // BAR_A: all waves done reading oth (s-1)
    __builtin_amdgcn_sched_barrier(0);
    STAGE(oth, s + 1);             // s=31: dummy wrap (k&31=0), never read
    asm volatile("s_waitcnt vmcnt(4)" ::: "memory");  // own slot-s loads done
    __builtin_amdgcn_s_barrier();  // BAR_B: slot s published across waves
    __builtin_amdgcn_sched_barrier(0);

    bf16x8 bg[4];
#pragma unroll
    for (int n = 0; n < 4; ++n)
      bg[n] = *(const bf16x8*)(cur + 4096 + (brow0 + n * 16) * 32 + sx);
    __builtin_amdgcn_s_setprio(1);
#pragma unroll
    for (int m = 0; m < 4; ++m) {
      bf16x8 af = *(const bf16x8*)(cur + (arow0 + m * 16) * 32 + sx);
#pragma unroll
      for (int n = 0; n < 4; ++n)
        acc[m][n] = __builtin_amdgcn_mfma_f32_16x16x32_bf16(af, bg[n], acc[m][n], 0, 0, 0);
    }
    __builtin_amdgcn_s_setprio(0);
    unsigned short* tmp_ = cur; cur = oth; oth = tmp_;  // swap buffers
  }
  asm volatile("s_waitcnt vmcnt(0) lgkmcnt(0)" ::: "memory");  // drain dummy

  // ---- epilogue: e=exp((dot-1)/T), diag masked; row/col partial sums ----
  // NO atomics: plain stores to tile-private planes (row partials keyed
  // (J,wn) -> planes 0..127; col partials keyed (I,wm) -> planes 128..255).
  float* rplane = part + (size_t)(2 * J + wn) * TWO_N;
  float* cplane = part + (size_t)(128 + 2 * I + wm) * TWO_N;
  float csum[4] = {0.f, 0.f, 0.f, 0.f};
#pragma unroll
  for (int m = 0; m < 4; ++m) {
#pragma unroll
    for (int r = 0; r < 4; ++r) {
      const int grow = rowA0 + wm * 64 + m * 16 + hi * 4 + r;  // row=(lane>>4)*4+reg
      float s = 0.f;
#pragma unroll
      for (int n = 0; n < 4; ++n) {
        const int gcol = colB0 + wn * 64 + n * 16 + lo;        // col=lane&15
        float e = exp2f((acc[m][n][r] - 1.0f) * EXP_SCALE);
        if (grow == gcol) e = 0.f;  // mask self-similarity (diag tiles)
        s += e;
        csum[n] += e;
      }
      s += __shfl_xor(s, 1); s += __shfl_xor(s, 2);
      s += __shfl_xor(s, 4); s += __shfl_xor(s, 8);
      if (lo == 0) rplane[grow] = s;  // 4 lanes, 64 distinct rows per wave
    }
  }
  if (!diag) {  // off-diagonal tiles feed transposed rows via col sums
#pragma unroll
    for (int n = 0; n < 4; ++n) {
      float s = csum[n];
      s += __shfl_xor(s, 16); s += __shfl_xor(s, 32);
      if (hi == 0) cplane[colB0 + wn * 64 + n * 16 + lo] = s;  // 16 lanes
    }
  }
#undef STAGE
}

// Fold only the provably-written plane entries -> per-row term -> mean.
// For row i (Ji = i>>7): row-planes 2J+{0,1} are written iff J >= Ji;
// col-planes 128+2I+{0,1} iff I < Ji. Exactly 128 entries per row, so no
// workspace memset is needed (stale bytes are never read).
__global__ __launch_bounds__(256) void reduce_finalize_kernel(
    const float* __restrict__ part, const float* __restrict__ pos,
    float* __restrict__ out) {
  const int i = blockIdx.x * 256 + threadIdx.x;
  const int Ji = i >> 7;
  float s = 0.f;
  for (int J = Ji; J < NT; ++J)
    s += part[(size_t)(2 * J) * TWO_N + i] + part[(size_t)(2 * J + 1) * TWO_N + i];
  for (int I = 0; I < Ji; ++I)
    s += part[(size_t)(128 + 2 * I) * TWO_N + i] +
         part[(size_t)(128 + 2 * I + 1) * TWO_N + i];
  float term = TEMP_INV + logf(s) - pos[i & (NN - 1)];
#pragma unroll
  for (int off = 1; off < 64; off <<= 1) term += __shfl_xor(term, off);
  __shared__ float tmp[4];
  const int t = threadIdx.x;
  if ((t & 63) == 0) tmp[t >> 6] = term;
  __syncthreads();
  if (t == 0)
    atomicAdd(out, (tmp[0] + tmp[1] + tmp[2] + tmp[3]) * (1.0f / (float)TWO_N));
}

extern "C" void kernel_launch(void* const* d_in, const int* in_sizes, int n_in,
                              void* d_out, int out_size, void* d_ws, size_t ws_size,
                              hipStream_t stream) {
  const float* z1 = (const float*)d_in[0];
  const float* z2 = (const float*)d_in[1];
  float* out = (float*)d_out;

  char* ws = (char*)d_ws;
  unsigned short* zb = (unsigned short*)ws;            // 16 MB bf16 z
  size_t off = (size_t)TWO_N * DIM * 2;
  float* part = (float*)(ws + off);                    // 8 MB: 256 x 8192 f32
  off += (size_t)256 * TWO_N * 4;
  float* pos = (float*)(ws + off);                     // 16 KB

  hipMemsetAsync(out, 0, sizeof(float), stream);
  prep_kernel<<<NN, 256, 0, stream>>>(z1, z2, zb, pos);
  lse_kernel<<<NBLK, 256, 0, stream>>>(zb, part);
  reduce_finalize_kernel<<<TWO_N / 256, 256, 0, stream>>>(part, pos, out);
}